// Round 3
// baseline (151.404 us; speedup 1.0000x reference)
//
#include <hip/hip_runtime.h>
#include <hip/hip_bf16.h>
#include <cstdint>

#define BS    16
#define NA    33600
#define NMAX  64
#define NC    80
#define NQ    20           // NC/4 float4 quads per anchor
#define TOPKN 13
#define SEG   16
#define SEGLEN (NA / SEG)   // 2100
#define EPSF  1e-9f

// ---- output layout (float32, concatenated flat in return order) ----
#define O_LAB 0
#define O_BOX 537600
#define O_SCR 2150400
#define O_FG  45158400
#define O_GT  45696000

// ---- workspace layout (bytes) ----
// topk  : 1024*13*4  = 53248       @ 0
// REGION A (time-shared):
//   s1val: 1024*16*13*4 = 851968   @ 53248      (K1a..K1b only)
//   s1idx: 851968                  @ 905216
//   counts: 537600*4 = 2150400     @ 53248      (memset AFTER K1b)
//   jsum  : 537600*4               @ 2203648
//   normv: 537600*4                @ 53248      (written by k_write AFTER k_resolve consumed counts)
// tgt   : 537600*4                 @ 4354048
// am    : 537600*4                 @ 6504448
// pos_align: 1024*4                @ 8654848
// pos_over : 1024*4                @ 8658944
// total: 8663040 bytes

// ============================================================
// K1a: per (row, segment): one wave scans SEGLEN anchors, outputs
// exact segment top-13 as (value, idx), tie-break (value desc, idx asc).
// ============================================================
__global__ __launch_bounds__(64) void k_topk_seg(
    const float* __restrict__ pd_scores,   // [BS,NA,NC]
    const float* __restrict__ pd_circles,  // [BS,NA,3]
    const float* __restrict__ anc,         // [NA,2]
    const int*   __restrict__ gt_labels,   // [BS,NMAX]
    const float* __restrict__ gt_bboxes,   // [BS,NMAX,3]
    const float* __restrict__ mask_gt,     // [BS,NMAX]
    float*       __restrict__ s1val,       // [1024*SEG, 13]
    int*         __restrict__ s1idx)
{
    const int blk  = blockIdx.x;        // row*SEG + seg
    const int row  = blk >> 4;
    const int seg  = blk & (SEG - 1);
    const int lane = threadIdx.x;

    float* outv = s1val + (size_t)blk * TOPKN;
    int*   outi = s1idx + (size_t)blk * TOPKN;

    if (mask_gt[row] <= 0.f) {
        if (lane < TOPKN) { outv[lane] = -2.f; outi[lane] = 0x7fffffff; }
        return;
    }

    const float gx = gt_bboxes[row * 3 + 0];
    const float gy = gt_bboxes[row * 3 + 1];
    const float gr = gt_bboxes[row * 3 + 2];
    const int   lbl = gt_labels[row];
    const int   b   = row >> 6;
    const float* __restrict__ ps = pd_scores + (size_t)b * NA * NC + lbl;
    const float* __restrict__ pc = pd_circles + (size_t)b * NA * 3;
    const float2* __restrict__ anc2 = (const float2*)anc;

    // per-lane sorted top-13 (value desc, anchor idx asc on ties)
    float tv[TOPKN]; int ti[TOPKN];
#pragma unroll
    for (int k = 0; k < TOPKN; ++k) { tv[k] = -1.f; ti[k] = 0x7fffffff; }

    const int base = seg * SEGLEN;
    for (int a = base + lane; a < base + SEGLEN; a += 64) {
        float2 ap = anc2[a];
        float dx = gx - ap.x, dy = gy - ap.y;
        float m = 0.f;
        if (sqrtf(dx * dx + dy * dy) <= gr) {
            float px = pc[a * 3 + 0], py = pc[a * 3 + 1], pr = pc[a * 3 + 2];
            float ddx = gx - px, ddy = gy - py;
            float d  = sqrtf(ddx * ddx + ddy * ddy);
            float rs = gr + pr;
            float iou = fmaxf((rs - d) / rs, 0.f);
            float i2 = iou * iou;
            m = ps[(size_t)a * NC] * (i2 * i2 * i2);
        }
        if (m > tv[TOPKN - 1]) {
            // static-index unrolled insertion (desc, stable: ties keep earlier idx first)
#pragma unroll
            for (int p = TOPKN - 1; p > 0; --p) {
                if (tv[p] < m) {
                    bool here = (tv[p - 1] >= m);
                    tv[p] = here ? m : tv[p - 1];
                    ti[p] = here ? a : ti[p - 1];
                }
            }
            if (tv[0] < m) { tv[0] = m; ti[0] = a; }
        }
    }

    // 13 extraction rounds: lists are sorted desc, so the global max of all
    // remaining candidates is some lane's head (slot 0). Butterfly argmax.
    float myv = -3.f; int myi = 0x7fffffff;
    for (int k = 0; k < TOPKN; ++k) {
        float v = tv[0]; int i = ti[0];
#pragma unroll
        for (int s = 1; s < 64; s <<= 1) {
            float vo = __shfl_xor(v, s);
            int   io = __shfl_xor(i, s);
            if (vo > v || (vo == v && io < i)) { v = vo; i = io; }
        }
        if (lane == k) { myv = v; myi = i; }
        bool own = (ti[0] == i);
        // owner shifts its list down one (static indices)
#pragma unroll
        for (int p = 0; p < TOPKN - 1; ++p) {
            tv[p] = own ? tv[p + 1] : tv[p];
            ti[p] = own ? ti[p + 1] : ti[p];
        }
        if (own) { tv[TOPKN - 1] = -3.f; ti[TOPKN - 1] = 0x7fffffff; }
    }
    if (lane < TOPKN) { outv[lane] = myv; outi[lane] = myi; }
}

// ============================================================
// K1b: per row: one wave merges SEG*13 = 208 segment candidates
// into the exact global top-13, applies topk_mask, writes indices.
// ============================================================
__global__ __launch_bounds__(64) void k_topk_merge(
    const float* __restrict__ s1val,
    const int*   __restrict__ s1idx,
    int*         __restrict__ topk_out)   // [1024,13]
{
    const int row  = blockIdx.x;
    const int lane = threadIdx.x;
    const float* __restrict__ v  = s1val + (size_t)row * SEG * TOPKN;
    const int*   __restrict__ ii = s1idx + (size_t)row * SEG * TOPKN;

    float sv[4]; int si[4];
#pragma unroll
    for (int q = 0; q < 4; ++q) {
        int c = lane + 64 * q;
        if (c < SEG * TOPKN) { sv[q] = v[c]; si[q] = ii[c]; }
        else                 { sv[q] = -3.f; si[q] = 0x7fffffff; }
    }

    float myv = -3.f; int myi = 0x7fffffff;
    for (int k = 0; k < TOPKN; ++k) {
        float bv = sv[0]; int bi = si[0];
#pragma unroll
        for (int q = 1; q < 4; ++q) {
            if (sv[q] > bv || (sv[q] == bv && si[q] < bi)) { bv = sv[q]; bi = si[q]; }
        }
#pragma unroll
        for (int s = 1; s < 64; s <<= 1) {
            float vo = __shfl_xor(bv, s);
            int   io = __shfl_xor(bi, s);
            if (vo > bv || (vo == bv && io < bi)) { bv = vo; bi = io; }
        }
        if (lane == k) { myv = bv; myi = bi; }
        // removal (idx unique for live rows; mass-removal of sentinels harmless)
#pragma unroll
        for (int q = 0; q < 4; ++q) {
            if (si[q] == bi && sv[q] == bv) sv[q] = -3.f;
        }
    }
    float w0 = __shfl(myv, 0);            // round-0 winner value = row max
    if (lane < TOPKN)
        topk_out[row * TOPKN + lane] = (w0 > EPSF) ? myi : -1;
}

// ============================================================
// K2: scatter claims (mask_pos before multi-resolution)
// ============================================================
__global__ __launch_bounds__(256) void k_claims(
    const float* __restrict__ anc,
    const float* __restrict__ gt_bboxes,
    const int*   __restrict__ topk,
    int*         __restrict__ counts,
    int*         __restrict__ jsum)
{
    int t = blockIdx.x * 256 + threadIdx.x;
    if (t >= BS * NMAX * TOPKN) return;
    int r = t / TOPKN;
    int a = topk[t];
    if (a < 0) return;
    int b = r >> 6, j = r & 63;
    float gx = gt_bboxes[r * 3 + 0], gy = gt_bboxes[r * 3 + 1], gr = gt_bboxes[r * 3 + 2];
    float dx = gx - anc[a * 2 + 0], dy = gy - anc[a * 2 + 1];
    if (sqrtf(dx * dx + dy * dy) <= gr) {     // mask_in_gts (mask_gt already 1 for live rows)
        atomicAdd(counts + b * NA + a, 1);
        atomicAdd(jsum + b * NA + a, j);
    }
}

// ============================================================
// K3: resolve multi-claim anchors, per-row pos_align/pos_over
// ============================================================
__global__ __launch_bounds__(256) void k_resolve(
    const float* __restrict__ pd_scores,
    const float* __restrict__ pd_circles,
    const float* __restrict__ anc,
    const int*   __restrict__ gt_labels,
    const float* __restrict__ gt_bboxes,
    const float* __restrict__ mask_gt,
    const int*   __restrict__ counts,
    const int*   __restrict__ jsum,
    int*         __restrict__ tgt_ws,
    float*       __restrict__ am_ws,
    unsigned*    __restrict__ pos_align,
    unsigned*    __restrict__ pos_over)
{
    int i = blockIdx.x * 256 + threadIdx.x;   // < BS*NA
    int b = i / NA, a = i - b * NA;
    int cnt = counts[i];
    float ax = anc[a * 2 + 0], ay = anc[a * 2 + 1];

    int tgt = -1;
    if (cnt == 1) {
        tgt = jsum[i];
    } else if (cnt > 1) {
        // argmax_j overlaps[b,j,a]  (masked IoU, first occurrence on ties)
        float px = pd_circles[((size_t)b * NA + a) * 3 + 0];
        float py = pd_circles[((size_t)b * NA + a) * 3 + 1];
        float pr = pd_circles[((size_t)b * NA + a) * 3 + 2];
        float best = -1.f; int bj = 0;
        for (int j = 0; j < NMAX; ++j) {
            int row = b * NMAX + j;
            float ov = 0.f;
            if (mask_gt[row] > 0.f) {
                float gx = gt_bboxes[row * 3 + 0], gy = gt_bboxes[row * 3 + 1], gr = gt_bboxes[row * 3 + 2];
                float dx = gx - ax, dy = gy - ay;
                if (sqrtf(dx * dx + dy * dy) <= gr) {
                    float ddx = gx - px, ddy = gy - py;
                    float d  = sqrtf(ddx * ddx + ddy * ddy);
                    float rs = gr + pr;
                    ov = fmaxf((rs - d) / rs, 0.f);
                }
            }
            if (ov > best) { best = ov; bj = j; }
        }
        tgt = bj;
    }
    tgt_ws[i] = tgt;

    float am = 0.f, ovv = 0.f;
    if (tgt >= 0) {
        int row = b * NMAX + tgt;
        if (mask_gt[row] > 0.f) {
            float gx = gt_bboxes[row * 3 + 0], gy = gt_bboxes[row * 3 + 1], gr = gt_bboxes[row * 3 + 2];
            float dx = gx - ax, dy = gy - ay;
            if (sqrtf(dx * dx + dy * dy) <= gr) {
                float px = pd_circles[((size_t)b * NA + a) * 3 + 0];
                float py = pd_circles[((size_t)b * NA + a) * 3 + 1];
                float pr = pd_circles[((size_t)b * NA + a) * 3 + 2];
                float ddx = gx - px, ddy = gy - py;
                float d  = sqrtf(ddx * ddx + ddy * ddy);
                float rs = gr + pr;
                float iou = fmaxf((rs - d) / rs, 0.f);
                float i2 = iou * iou;
                float s  = pd_scores[((size_t)b * NA + a) * NC + gt_labels[row]];
                am  = s * (i2 * i2 * i2);
                ovv = iou;
            }
        }
        atomicMax(pos_align + row, __float_as_uint(am));
        atomicMax(pos_over  + row, __float_as_uint(ovv));
    }
    am_ws[i] = am;
}

// ============================================================
// K4: write labels/boxes/fg/gt outputs + compact per-anchor norm
// ============================================================
__global__ __launch_bounds__(256) void k_write(
    const int*      __restrict__ gt_labels,
    const float*    __restrict__ gt_bboxes,
    const int*      __restrict__ tgt_ws,
    const float*    __restrict__ am_ws,
    const unsigned* __restrict__ pos_align,
    const unsigned* __restrict__ pos_over,
    float*          __restrict__ out,
    float*          __restrict__ normv)
{
    int i = blockIdx.x * 256 + threadIdx.x;   // < BS*NA
    int b = i / NA;
    int tgt = tgt_ws[i];
    bool fg = (tgt >= 0);
    int jj  = fg ? tgt : 0;
    int row = b * NMAX + jj;

    int lbl = max(gt_labels[row], 0);
    out[O_LAB + i] = (float)lbl;
    out[O_BOX + (size_t)i * 3 + 0] = gt_bboxes[row * 3 + 0];
    out[O_BOX + (size_t)i * 3 + 1] = gt_bboxes[row * 3 + 1];
    out[O_BOX + (size_t)i * 3 + 2] = gt_bboxes[row * 3 + 2];
    out[O_FG + i] = fg ? 1.f : 0.f;
    out[O_GT + i] = (float)jj;

    float nv = 0.f;
    if (fg) {
        float pa = __uint_as_float(pos_align[row]);
        float po = __uint_as_float(pos_over[row]);
        nv = am_ws[i] * po / (pa + EPSF);
    }
    normv[i] = nv;   // one_hot * fg * norm: row is all-zero iff nv==0 contributes nothing
}

// ============================================================
// K5: stream the full scores tensor with coalesced float4 stores
// ============================================================
__global__ __launch_bounds__(256) void k_scores(
    const float* __restrict__ normv,     // [BS*NA]
    const float* __restrict__ out_lab,   // out + O_LAB
    float4*      __restrict__ scr)       // out + O_SCR viewed as float4
{
    const int total = BS * NA * NQ;      // 10,752,000 float4s
    for (int f = blockIdx.x * 256 + threadIdx.x; f < total; f += gridDim.x * 256) {
        int i = f / NQ;
        int q = f - i * NQ;
        float nv  = normv[i];
        int   lbl = (int)out_lab[i];
        int   c0  = q * 4;
        float4 v; v.x = 0.f; v.y = 0.f; v.z = 0.f; v.w = 0.f;
        if      (lbl == c0)     v.x = nv;
        else if (lbl == c0 + 1) v.y = nv;
        else if (lbl == c0 + 2) v.z = nv;
        else if (lbl == c0 + 3) v.w = nv;
        scr[f] = v;
    }
}

// ============================================================
extern "C" void kernel_launch(void* const* d_in, const int* in_sizes, int n_in,
                              void* d_out, int out_size, void* d_ws, size_t ws_size,
                              hipStream_t stream) {
    const float* pd_scores  = (const float*)d_in[0];
    const float* pd_circles = (const float*)d_in[1];
    const float* anc        = (const float*)d_in[2];
    const int*   gt_labels  = (const int*)d_in[3];
    const float* gt_bboxes  = (const float*)d_in[4];
    const float* mask_gt    = (const float*)d_in[5];
    float* out = (float*)d_out;

    char* ws = (char*)d_ws;
    int*      topk      = (int*)(ws + 0);
    float*    s1val     = (float*)(ws + 53248);      // time-shared with counts / normv
    int*      s1idx     = (int*)(ws + 905216);
    int*      counts    = (int*)(ws + 53248);
    int*      jsum      = (int*)(ws + 2203648);
    float*    normv     = (float*)(ws + 53248);      // reuses counts region after k_resolve
    int*      tgt_ws    = (int*)(ws + 4354048);
    float*    am_ws     = (float*)(ws + 6504448);
    unsigned* pos_align = (unsigned*)(ws + 8654848);
    unsigned* pos_over  = (unsigned*)(ws + 8658944);

    hipMemsetAsync(pos_align, 0, 2 * 1024 * sizeof(unsigned), stream);

    k_topk_seg<<<BS * NMAX * SEG, 64, 0, stream>>>(pd_scores, pd_circles, anc, gt_labels,
                                                   gt_bboxes, mask_gt, s1val, s1idx);
    k_topk_merge<<<BS * NMAX, 64, 0, stream>>>(s1val, s1idx, topk);

    // counts/jsum share bytes with s1val/s1idx — zero only after the merge
    hipMemsetAsync(counts, 0, 2 * 537600 * sizeof(int), stream);

    k_claims<<<(BS * NMAX * TOPKN + 255) / 256, 256, 0, stream>>>(anc, gt_bboxes, topk,
                                                                  counts, jsum);
    k_resolve<<<(BS * NA) / 256, 256, 0, stream>>>(pd_scores, pd_circles, anc, gt_labels,
                                                   gt_bboxes, mask_gt, counts, jsum,
                                                   tgt_ws, am_ws, pos_align, pos_over);
    k_write<<<(BS * NA) / 256, 256, 0, stream>>>(gt_labels, gt_bboxes, tgt_ws, am_ws,
                                                 pos_align, pos_over, out, normv);
    k_scores<<<4096, 256, 0, stream>>>(normv, out + O_LAB, (float4*)(out + O_SCR));
}

// Round 4
// 147.495 us; speedup vs baseline: 1.0265x; 1.0265x over previous
//
#include <hip/hip_runtime.h>
#include <hip/hip_bf16.h>
#include <cstdint>

#define BS    16
#define NA    33600
#define NMAX  64
#define NC    80
#define NQ    20           // NC/4 float4 quads per anchor
#define TOPKN 13
#define SEG   16
#define SEGLEN (NA / SEG)   // 2100
#define EPSF  1e-9f

// ---- output layout (float32, concatenated flat in return order) ----
#define O_LAB 0
#define O_BOX 537600
#define O_SCR 2150400
#define O_FG  45158400
#define O_GT  45696000

// ---- workspace layout (bytes) ----
// topk  : 1024*13*4  = 53248       @ 0
// REGION A (time-shared):
//   s1val: 1024*16*13*4 = 851968   @ 53248      (K1a..K1b only)
//   s1idx: 851968                  @ 905216
//   counts: 537600*4 = 2150400     @ 53248      (k_zero AFTER K1b)
//   jsum  : 537600*4               @ 2203648
//   normv: 537600*4                @ 53248      (written by k_write AFTER k_resolve consumed counts)
// tgt   : 537600*4                 @ 4354048
// am    : 537600*4                 @ 6504448
// pos_align: 1024*4                @ 8654848    (zeroed by k_topk_seg seg==0 blocks)
// pos_over : 1024*4                @ 8658944
// total: 8663040 bytes
// NO hipMemsetAsync anywhere: in-graph memset nodes cost ~110us fixed (R2/R3 measured).

// ============================================================
// K1a: per (row, segment): one wave scans SEGLEN anchors, outputs
// exact segment top-13 as (value, idx), tie-break (value desc, idx asc).
// seg==0 blocks also zero pos_align/pos_over for their row.
// ============================================================
__global__ __launch_bounds__(64) void k_topk_seg(
    const float* __restrict__ pd_scores,   // [BS,NA,NC]
    const float* __restrict__ pd_circles,  // [BS,NA,3]
    const float* __restrict__ anc,         // [NA,2]
    const int*   __restrict__ gt_labels,   // [BS,NMAX]
    const float* __restrict__ gt_bboxes,   // [BS,NMAX,3]
    const float* __restrict__ mask_gt,     // [BS,NMAX]
    float*       __restrict__ s1val,       // [1024*SEG, 13]
    int*         __restrict__ s1idx,
    unsigned*    __restrict__ pos_align,   // [1024]
    unsigned*    __restrict__ pos_over)    // [1024]
{
    const int blk  = blockIdx.x;        // row*SEG + seg
    const int row  = blk >> 4;
    const int seg  = blk & (SEG - 1);
    const int lane = threadIdx.x;

    if (seg == 0 && lane == 0) {        // zero pos arrays (consumed by k_resolve, 2 kernels later)
        pos_align[row] = 0u;
        pos_over[row]  = 0u;
    }

    float* outv = s1val + (size_t)blk * TOPKN;
    int*   outi = s1idx + (size_t)blk * TOPKN;

    if (mask_gt[row] <= 0.f) {
        if (lane < TOPKN) { outv[lane] = -2.f; outi[lane] = 0x7fffffff; }
        return;
    }

    const float gx = gt_bboxes[row * 3 + 0];
    const float gy = gt_bboxes[row * 3 + 1];
    const float gr = gt_bboxes[row * 3 + 2];
    const int   lbl = gt_labels[row];
    const int   b   = row >> 6;
    const float* __restrict__ ps = pd_scores + (size_t)b * NA * NC + lbl;
    const float* __restrict__ pc = pd_circles + (size_t)b * NA * 3;
    const float2* __restrict__ anc2 = (const float2*)anc;

    // per-lane sorted top-13 (value desc, anchor idx asc on ties)
    float tv[TOPKN]; int ti[TOPKN];
#pragma unroll
    for (int k = 0; k < TOPKN; ++k) { tv[k] = -1.f; ti[k] = 0x7fffffff; }

    const int base = seg * SEGLEN;
    for (int a = base + lane; a < base + SEGLEN; a += 64) {
        float2 ap = anc2[a];
        float dx = gx - ap.x, dy = gy - ap.y;
        float m = 0.f;
        if (sqrtf(dx * dx + dy * dy) <= gr) {
            float px = pc[a * 3 + 0], py = pc[a * 3 + 1], pr = pc[a * 3 + 2];
            float ddx = gx - px, ddy = gy - py;
            float d  = sqrtf(ddx * ddx + ddy * ddy);
            float rs = gr + pr;
            float iou = fmaxf((rs - d) / rs, 0.f);
            float i2 = iou * iou;
            m = ps[(size_t)a * NC] * (i2 * i2 * i2);
        }
        if (m > tv[TOPKN - 1]) {
            // static-index unrolled insertion (desc, stable: ties keep earlier idx first)
#pragma unroll
            for (int p = TOPKN - 1; p > 0; --p) {
                if (tv[p] < m) {
                    bool here = (tv[p - 1] >= m);
                    tv[p] = here ? m : tv[p - 1];
                    ti[p] = here ? a : ti[p - 1];
                }
            }
            if (tv[0] < m) { tv[0] = m; ti[0] = a; }
        }
    }

    // 13 extraction rounds: lists sorted desc -> global max is some lane's head.
    float myv = -3.f; int myi = 0x7fffffff;
    for (int k = 0; k < TOPKN; ++k) {
        float v = tv[0]; int i = ti[0];
#pragma unroll
        for (int s = 1; s < 64; s <<= 1) {
            float vo = __shfl_xor(v, s);
            int   io = __shfl_xor(i, s);
            if (vo > v || (vo == v && io < i)) { v = vo; i = io; }
        }
        if (lane == k) { myv = v; myi = i; }
        bool own = (ti[0] == i);
#pragma unroll
        for (int p = 0; p < TOPKN - 1; ++p) {
            tv[p] = own ? tv[p + 1] : tv[p];
            ti[p] = own ? ti[p + 1] : ti[p];
        }
        if (own) { tv[TOPKN - 1] = -3.f; ti[TOPKN - 1] = 0x7fffffff; }
    }
    if (lane < TOPKN) { outv[lane] = myv; outi[lane] = myi; }
}

// ============================================================
// K1b: per row: one wave merges SEG*13 = 208 segment candidates
// into the exact global top-13, applies topk_mask, writes indices.
// ============================================================
__global__ __launch_bounds__(64) void k_topk_merge(
    const float* __restrict__ s1val,
    const int*   __restrict__ s1idx,
    int*         __restrict__ topk_out)   // [1024,13]
{
    const int row  = blockIdx.x;
    const int lane = threadIdx.x;
    const float* __restrict__ v  = s1val + (size_t)row * SEG * TOPKN;
    const int*   __restrict__ ii = s1idx + (size_t)row * SEG * TOPKN;

    float sv[4]; int si[4];
#pragma unroll
    for (int q = 0; q < 4; ++q) {
        int c = lane + 64 * q;
        if (c < SEG * TOPKN) { sv[q] = v[c]; si[q] = ii[c]; }
        else                 { sv[q] = -3.f; si[q] = 0x7fffffff; }
    }

    float myv = -3.f; int myi = 0x7fffffff;
    for (int k = 0; k < TOPKN; ++k) {
        float bv = sv[0]; int bi = si[0];
#pragma unroll
        for (int q = 1; q < 4; ++q) {
            if (sv[q] > bv || (sv[q] == bv && si[q] < bi)) { bv = sv[q]; bi = si[q]; }
        }
#pragma unroll
        for (int s = 1; s < 64; s <<= 1) {
            float vo = __shfl_xor(bv, s);
            int   io = __shfl_xor(bi, s);
            if (vo > bv || (vo == bv && io < bi)) { bv = vo; bi = io; }
        }
        if (lane == k) { myv = bv; myi = bi; }
#pragma unroll
        for (int q = 0; q < 4; ++q) {
            if (si[q] == bi && sv[q] == bv) sv[q] = -3.f;
        }
    }
    float w0 = __shfl(myv, 0);            // round-0 winner value = row max
    if (lane < TOPKN)
        topk_out[row * TOPKN + lane] = (w0 > EPSF) ? myi : -1;
}

// ============================================================
// K1c: zero counts+jsum (overlaps s1val/s1idx -> must run after merge)
// ============================================================
__global__ __launch_bounds__(256) void k_zero(float4* __restrict__ p, int n4)
{
    int t = blockIdx.x * 256 + threadIdx.x;
    if (t < n4) {
        float4 z; z.x = 0.f; z.y = 0.f; z.z = 0.f; z.w = 0.f;
        p[t] = z;
    }
}

// ============================================================
// K2: scatter claims (mask_pos before multi-resolution)
// ============================================================
__global__ __launch_bounds__(256) void k_claims(
    const float* __restrict__ anc,
    const float* __restrict__ gt_bboxes,
    const int*   __restrict__ topk,
    int*         __restrict__ counts,
    int*         __restrict__ jsum)
{
    int t = blockIdx.x * 256 + threadIdx.x;
    if (t >= BS * NMAX * TOPKN) return;
    int r = t / TOPKN;
    int a = topk[t];
    if (a < 0) return;
    int b = r >> 6, j = r & 63;
    float gx = gt_bboxes[r * 3 + 0], gy = gt_bboxes[r * 3 + 1], gr = gt_bboxes[r * 3 + 2];
    float dx = gx - anc[a * 2 + 0], dy = gy - anc[a * 2 + 1];
    if (sqrtf(dx * dx + dy * dy) <= gr) {     // mask_in_gts (mask_gt already 1 for live rows)
        atomicAdd(counts + b * NA + a, 1);
        atomicAdd(jsum + b * NA + a, j);
    }
}

// ============================================================
// K3: resolve multi-claim anchors, per-row pos_align/pos_over
// ============================================================
__global__ __launch_bounds__(256) void k_resolve(
    const float* __restrict__ pd_scores,
    const float* __restrict__ pd_circles,
    const float* __restrict__ anc,
    const int*   __restrict__ gt_labels,
    const float* __restrict__ gt_bboxes,
    const float* __restrict__ mask_gt,
    const int*   __restrict__ counts,
    const int*   __restrict__ jsum,
    int*         __restrict__ tgt_ws,
    float*       __restrict__ am_ws,
    unsigned*    __restrict__ pos_align,
    unsigned*    __restrict__ pos_over)
{
    int i = blockIdx.x * 256 + threadIdx.x;   // < BS*NA
    int b = i / NA, a = i - b * NA;
    int cnt = counts[i];
    float ax = anc[a * 2 + 0], ay = anc[a * 2 + 1];

    int tgt = -1;
    if (cnt == 1) {
        tgt = jsum[i];
    } else if (cnt > 1) {
        // argmax_j overlaps[b,j,a]  (masked IoU, first occurrence on ties)
        float px = pd_circles[((size_t)b * NA + a) * 3 + 0];
        float py = pd_circles[((size_t)b * NA + a) * 3 + 1];
        float pr = pd_circles[((size_t)b * NA + a) * 3 + 2];
        float best = -1.f; int bj = 0;
        for (int j = 0; j < NMAX; ++j) {
            int row = b * NMAX + j;
            float ov = 0.f;
            if (mask_gt[row] > 0.f) {
                float gx = gt_bboxes[row * 3 + 0], gy = gt_bboxes[row * 3 + 1], gr = gt_bboxes[row * 3 + 2];
                float dx = gx - ax, dy = gy - ay;
                if (sqrtf(dx * dx + dy * dy) <= gr) {
                    float ddx = gx - px, ddy = gy - py;
                    float d  = sqrtf(ddx * ddx + ddy * ddy);
                    float rs = gr + pr;
                    ov = fmaxf((rs - d) / rs, 0.f);
                }
            }
            if (ov > best) { best = ov; bj = j; }
        }
        tgt = bj;
    }
    tgt_ws[i] = tgt;

    float am = 0.f, ovv = 0.f;
    if (tgt >= 0) {
        int row = b * NMAX + tgt;
        if (mask_gt[row] > 0.f) {
            float gx = gt_bboxes[row * 3 + 0], gy = gt_bboxes[row * 3 + 1], gr = gt_bboxes[row * 3 + 2];
            float dx = gx - ax, dy = gy - ay;
            if (sqrtf(dx * dx + dy * dy) <= gr) {
                float px = pd_circles[((size_t)b * NA + a) * 3 + 0];
                float py = pd_circles[((size_t)b * NA + a) * 3 + 1];
                float pr = pd_circles[((size_t)b * NA + a) * 3 + 2];
                float ddx = gx - px, ddy = gy - py;
                float d  = sqrtf(ddx * ddx + ddy * ddy);
                float rs = gr + pr;
                float iou = fmaxf((rs - d) / rs, 0.f);
                float i2 = iou * iou;
                float s  = pd_scores[((size_t)b * NA + a) * NC + gt_labels[row]];
                am  = s * (i2 * i2 * i2);
                ovv = iou;
            }
        }
        atomicMax(pos_align + row, __float_as_uint(am));
        atomicMax(pos_over  + row, __float_as_uint(ovv));
    }
    am_ws[i] = am;
}

// ============================================================
// K4: write labels/boxes/fg/gt outputs + compact per-anchor norm
// ============================================================
__global__ __launch_bounds__(256) void k_write(
    const int*      __restrict__ gt_labels,
    const float*    __restrict__ gt_bboxes,
    const int*      __restrict__ tgt_ws,
    const float*    __restrict__ am_ws,
    const unsigned* __restrict__ pos_align,
    const unsigned* __restrict__ pos_over,
    float*          __restrict__ out,
    float*          __restrict__ normv)
{
    int i = blockIdx.x * 256 + threadIdx.x;   // < BS*NA
    int b = i / NA;
    int tgt = tgt_ws[i];
    bool fg = (tgt >= 0);
    int jj  = fg ? tgt : 0;
    int row = b * NMAX + jj;

    int lbl = max(gt_labels[row], 0);
    out[O_LAB + i] = (float)lbl;
    out[O_BOX + (size_t)i * 3 + 0] = gt_bboxes[row * 3 + 0];
    out[O_BOX + (size_t)i * 3 + 1] = gt_bboxes[row * 3 + 1];
    out[O_BOX + (size_t)i * 3 + 2] = gt_bboxes[row * 3 + 2];
    out[O_FG + i] = fg ? 1.f : 0.f;
    out[O_GT + i] = (float)jj;

    float nv = 0.f;
    if (fg) {
        float pa = __uint_as_float(pos_align[row]);
        float po = __uint_as_float(pos_over[row]);
        nv = am_ws[i] * po / (pa + EPSF);
    }
    normv[i] = nv;
}

// ============================================================
// K5: stream the full scores tensor with coalesced float4 stores
// ============================================================
__global__ __launch_bounds__(256) void k_scores(
    const float* __restrict__ normv,     // [BS*NA]
    const float* __restrict__ out_lab,   // out + O_LAB
    float4*      __restrict__ scr)       // out + O_SCR viewed as float4
{
    const int total = BS * NA * NQ;      // 10,752,000 float4s
    for (int f = blockIdx.x * 256 + threadIdx.x; f < total; f += gridDim.x * 256) {
        int i = f / NQ;
        int q = f - i * NQ;
        float nv  = normv[i];
        int   lbl = (int)out_lab[i];
        int   c0  = q * 4;
        float4 v; v.x = 0.f; v.y = 0.f; v.z = 0.f; v.w = 0.f;
        if      (lbl == c0)     v.x = nv;
        else if (lbl == c0 + 1) v.y = nv;
        else if (lbl == c0 + 2) v.z = nv;
        else if (lbl == c0 + 3) v.w = nv;
        scr[f] = v;
    }
}

// ============================================================
extern "C" void kernel_launch(void* const* d_in, const int* in_sizes, int n_in,
                              void* d_out, int out_size, void* d_ws, size_t ws_size,
                              hipStream_t stream) {
    const float* pd_scores  = (const float*)d_in[0];
    const float* pd_circles = (const float*)d_in[1];
    const float* anc        = (const float*)d_in[2];
    const int*   gt_labels  = (const int*)d_in[3];
    const float* gt_bboxes  = (const float*)d_in[4];
    const float* mask_gt    = (const float*)d_in[5];
    float* out = (float*)d_out;

    char* ws = (char*)d_ws;
    int*      topk      = (int*)(ws + 0);
    float*    s1val     = (float*)(ws + 53248);      // time-shared with counts / normv
    int*      s1idx     = (int*)(ws + 905216);
    int*      counts    = (int*)(ws + 53248);
    int*      jsum      = (int*)(ws + 2203648);
    float*    normv     = (float*)(ws + 53248);      // reuses counts region after k_resolve
    int*      tgt_ws    = (int*)(ws + 4354048);
    float*    am_ws     = (float*)(ws + 6504448);
    unsigned* pos_align = (unsigned*)(ws + 8654848);
    unsigned* pos_over  = (unsigned*)(ws + 8658944);

    k_topk_seg<<<BS * NMAX * SEG, 64, 0, stream>>>(pd_scores, pd_circles, anc, gt_labels,
                                                   gt_bboxes, mask_gt, s1val, s1idx,
                                                   pos_align, pos_over);
    k_topk_merge<<<BS * NMAX, 64, 0, stream>>>(s1val, s1idx, topk);

    // counts/jsum (4.3 MB, overlaps s1val/s1idx) — zero with our own kernel,
    // NOT hipMemsetAsync (in-graph memset node costs ~110us fixed).
    const int n4 = (2 * 537600) / 4;     // 268,800 float4s
    k_zero<<<(n4 + 255) / 256, 256, 0, stream>>>((float4*)counts, n4);

    k_claims<<<(BS * NMAX * TOPKN + 255) / 256, 256, 0, stream>>>(anc, gt_bboxes, topk,
                                                                  counts, jsum);
    k_resolve<<<(BS * NA) / 256, 256, 0, stream>>>(pd_scores, pd_circles, anc, gt_labels,
                                                   gt_bboxes, mask_gt, counts, jsum,
                                                   tgt_ws, am_ws, pos_align, pos_over);
    k_write<<<(BS * NA) / 256, 256, 0, stream>>>(gt_labels, gt_bboxes, tgt_ws, am_ws,
                                                 pos_align, pos_over, out, normv);
    k_scores<<<4096, 256, 0, stream>>>(normv, out + O_LAB, (float4*)(out + O_SCR));
}

// Round 5
// 139.164 us; speedup vs baseline: 1.0880x; 1.0599x over previous
//
#include <hip/hip_runtime.h>
#include <hip/hip_bf16.h>
#include <cstdint>

#define BS    16
#define NA    33600
#define NMAX  64
#define NC    80
#define NQ    20           // NC/4 float4 quads per anchor
#define TOPKN 13
#define SEG   16
#define SEGLEN (NA / SEG)   // 2100
#define EPSF  1e-9f

// ---- output layout (float32, concatenated flat in return order) ----
#define O_LAB 0
#define O_BOX 537600
#define O_SCR 2150400
#define O_FG  45158400
#define O_GT  45696000

// ---- workspace layout (bytes), fully NON-overlapping (8.16 MB total) ----
// s1val @ 0        : 1024*16*13*4 = 851968
// s1idx @ 851968   : 851968          (end 1703936)
// pack  @ 1703936  : 537600*4        (end 3854336)  claim pack: (cnt<<20)|jsum
// tgt   @ 3854336  : 537600*4        (end 6004736)
// am    @ 6004736  : 537600*4        (end 8155136)
// pos_align @ 8155136: 4096 ; pos_over @ 8159232: 4096  (end 8163328)
// pack zeroed inside k_topk_seg (grid-stride); pos zeroed by seg==0 blocks.
// NO hipMemsetAsync anywhere; timed window = ~110us harness poison-restore
// (structural, per-replay) + our 4 kernels.

// ============================================================
// K1: per (row, segment): one wave scans SEGLEN anchors, outputs
// exact segment top-13 as (value, idx), tie-break (value desc, idx asc).
// Also zeros pack[] (grid-stride) and pos arrays (seg==0 blocks).
// ============================================================
__global__ __launch_bounds__(64) void k_topk_seg(
    const float* __restrict__ pd_scores,   // [BS,NA,NC]
    const float* __restrict__ pd_circles,  // [BS,NA,3]
    const float* __restrict__ anc,         // [NA,2]
    const int*   __restrict__ gt_labels,   // [BS,NMAX]
    const float* __restrict__ gt_bboxes,   // [BS,NMAX,3]
    const float* __restrict__ mask_gt,     // [BS,NMAX]
    float*       __restrict__ s1val,       // [1024*SEG, 13]
    int*         __restrict__ s1idx,
    unsigned*    __restrict__ pack,        // [BS*NA]
    unsigned*    __restrict__ pos_align,   // [1024]
    unsigned*    __restrict__ pos_over)    // [1024]
{
    const int blk  = blockIdx.x;        // row*SEG + seg
    const int row  = blk >> 4;
    const int seg  = blk & (SEG - 1);
    const int lane = threadIdx.x;

    // zero pack: 1,048,576 threads cover 537,600 words
    {
        int gtid = blk * 64 + lane;
        if (gtid < BS * NA) pack[gtid] = 0u;
    }
    if (seg == 0 && lane == 0) {        // zero pos arrays (consumed by k_resolve)
        pos_align[row] = 0u;
        pos_over[row]  = 0u;
    }

    float* outv = s1val + (size_t)blk * TOPKN;
    int*   outi = s1idx + (size_t)blk * TOPKN;

    if (mask_gt[row] <= 0.f) {
        if (lane < TOPKN) { outv[lane] = -2.f; outi[lane] = 0x7fffffff; }
        return;
    }

    const float gx = gt_bboxes[row * 3 + 0];
    const float gy = gt_bboxes[row * 3 + 1];
    const float gr = gt_bboxes[row * 3 + 2];
    const int   lbl = gt_labels[row];
    const int   b   = row >> 6;
    const float* __restrict__ ps = pd_scores + (size_t)b * NA * NC + lbl;
    const float* __restrict__ pc = pd_circles + (size_t)b * NA * 3;
    const float2* __restrict__ anc2 = (const float2*)anc;

    // per-lane sorted top-13 (value desc, anchor idx asc on ties)
    float tv[TOPKN]; int ti[TOPKN];
#pragma unroll
    for (int k = 0; k < TOPKN; ++k) { tv[k] = -1.f; ti[k] = 0x7fffffff; }

    const int base = seg * SEGLEN;
    for (int a = base + lane; a < base + SEGLEN; a += 64) {
        float2 ap = anc2[a];
        float dx = gx - ap.x, dy = gy - ap.y;
        float m = 0.f;
        if (sqrtf(dx * dx + dy * dy) <= gr) {
            float px = pc[a * 3 + 0], py = pc[a * 3 + 1], pr = pc[a * 3 + 2];
            float ddx = gx - px, ddy = gy - py;
            float d  = sqrtf(ddx * ddx + ddy * ddy);
            float rs = gr + pr;
            float iou = fmaxf((rs - d) / rs, 0.f);
            float i2 = iou * iou;
            m = ps[(size_t)a * NC] * (i2 * i2 * i2);
        }
        if (m > tv[TOPKN - 1]) {
            // static-index unrolled insertion (desc, stable: ties keep earlier idx first)
#pragma unroll
            for (int p = TOPKN - 1; p > 0; --p) {
                if (tv[p] < m) {
                    bool here = (tv[p - 1] >= m);
                    tv[p] = here ? m : tv[p - 1];
                    ti[p] = here ? a : ti[p - 1];
                }
            }
            if (tv[0] < m) { tv[0] = m; ti[0] = a; }
        }
    }

    // 13 extraction rounds: lists sorted desc -> global max is some lane's head.
    float myv = -3.f; int myi = 0x7fffffff;
    for (int k = 0; k < TOPKN; ++k) {
        float v = tv[0]; int i = ti[0];
#pragma unroll
        for (int s = 1; s < 64; s <<= 1) {
            float vo = __shfl_xor(v, s);
            int   io = __shfl_xor(i, s);
            if (vo > v || (vo == v && io < i)) { v = vo; i = io; }
        }
        if (lane == k) { myv = v; myi = i; }
        bool own = (ti[0] == i);
#pragma unroll
        for (int p = 0; p < TOPKN - 1; ++p) {
            tv[p] = own ? tv[p + 1] : tv[p];
            ti[p] = own ? ti[p + 1] : ti[p];
        }
        if (own) { tv[TOPKN - 1] = -3.f; ti[TOPKN - 1] = 0x7fffffff; }
    }
    if (lane < TOPKN) { outv[lane] = myv; outi[lane] = myi; }
}

// ============================================================
// K2: per row: merge SEG*13 = 208 candidates into exact global top-13,
// apply topk_mask, and claim directly: atomicAdd pack (cnt<<20)|j for
// in-circle winners. (Claims counted per reference AFTER mask_in_gts.)
// ============================================================
__global__ __launch_bounds__(64) void k_merge_claim(
    const float* __restrict__ s1val,
    const int*   __restrict__ s1idx,
    const float* __restrict__ anc,
    const float* __restrict__ gt_bboxes,
    unsigned*    __restrict__ pack)
{
    const int row  = blockIdx.x;
    const int lane = threadIdx.x;
    const float* __restrict__ v  = s1val + (size_t)row * SEG * TOPKN;
    const int*   __restrict__ ii = s1idx + (size_t)row * SEG * TOPKN;

    float sv[4]; int si[4];
#pragma unroll
    for (int q = 0; q < 4; ++q) {
        int c = lane + 64 * q;
        if (c < SEG * TOPKN) { sv[q] = v[c]; si[q] = ii[c]; }
        else                 { sv[q] = -3.f; si[q] = 0x7fffffff; }
    }

    float myv = -3.f; int myi = 0x7fffffff;
    for (int k = 0; k < TOPKN; ++k) {
        float bv = sv[0]; int bi = si[0];
#pragma unroll
        for (int q = 1; q < 4; ++q) {
            if (sv[q] > bv || (sv[q] == bv && si[q] < bi)) { bv = sv[q]; bi = si[q]; }
        }
#pragma unroll
        for (int s = 1; s < 64; s <<= 1) {
            float vo = __shfl_xor(bv, s);
            int   io = __shfl_xor(bi, s);
            if (vo > bv || (vo == bv && io < bi)) { bv = vo; bi = io; }
        }
        if (lane == k) { myv = bv; myi = bi; }
#pragma unroll
        for (int q = 0; q < 4; ++q) {
            if (si[q] == bi && sv[q] == bv) sv[q] = -3.f;
        }
    }
    float w0 = __shfl(myv, 0);            // round-0 winner value = row max
    // claims: all 13 winners of a live row (w0 > EPS), filtered by in-circle
    if (lane < TOPKN && w0 > EPSF) {
        int a = myi;                      // always a real anchor index (208 >= 13 real cands)
        float gx = gt_bboxes[row * 3 + 0];
        float gy = gt_bboxes[row * 3 + 1];
        float gr = gt_bboxes[row * 3 + 2];
        float dx = gx - anc[a * 2 + 0], dy = gy - anc[a * 2 + 1];
        if (sqrtf(dx * dx + dy * dy) <= gr) {
            int b = row >> 6, j = row & 63;
            atomicAdd(pack + b * NA + a, (1u << 20) | (unsigned)j);
        }
    }
}

// ============================================================
// K3: resolve multi-claim anchors, per-row pos_align/pos_over
// ============================================================
__global__ __launch_bounds__(256) void k_resolve(
    const float* __restrict__ pd_scores,
    const float* __restrict__ pd_circles,
    const float* __restrict__ anc,
    const int*   __restrict__ gt_labels,
    const float* __restrict__ gt_bboxes,
    const float* __restrict__ mask_gt,
    const unsigned* __restrict__ pack,
    int*         __restrict__ tgt_ws,
    float*       __restrict__ am_ws,
    unsigned*    __restrict__ pos_align,
    unsigned*    __restrict__ pos_over)
{
    int i = blockIdx.x * 256 + threadIdx.x;   // < BS*NA
    int b = i / NA, a = i - b * NA;
    unsigned p = pack[i];
    int cnt = (int)(p >> 20);
    float ax = anc[a * 2 + 0], ay = anc[a * 2 + 1];

    int tgt = -1;
    if (cnt == 1) {
        tgt = (int)(p & 0xFFFFFu);
    } else if (cnt > 1) {
        // argmax_j overlaps[b,j,a]  (masked IoU, first occurrence on ties)
        float px = pd_circles[((size_t)b * NA + a) * 3 + 0];
        float py = pd_circles[((size_t)b * NA + a) * 3 + 1];
        float pr = pd_circles[((size_t)b * NA + a) * 3 + 2];
        float best = -1.f; int bj = 0;
        for (int j = 0; j < NMAX; ++j) {
            int row = b * NMAX + j;
            float ov = 0.f;
            if (mask_gt[row] > 0.f) {
                float gx = gt_bboxes[row * 3 + 0], gy = gt_bboxes[row * 3 + 1], gr = gt_bboxes[row * 3 + 2];
                float dx = gx - ax, dy = gy - ay;
                if (sqrtf(dx * dx + dy * dy) <= gr) {
                    float ddx = gx - px, ddy = gy - py;
                    float d  = sqrtf(ddx * ddx + ddy * ddy);
                    float rs = gr + pr;
                    ov = fmaxf((rs - d) / rs, 0.f);
                }
            }
            if (ov > best) { best = ov; bj = j; }
        }
        tgt = bj;
    }
    tgt_ws[i] = tgt;

    float am = 0.f, ovv = 0.f;
    if (tgt >= 0) {
        int row = b * NMAX + tgt;
        if (mask_gt[row] > 0.f) {
            float gx = gt_bboxes[row * 3 + 0], gy = gt_bboxes[row * 3 + 1], gr = gt_bboxes[row * 3 + 2];
            float dx = gx - ax, dy = gy - ay;
            if (sqrtf(dx * dx + dy * dy) <= gr) {
                float px = pd_circles[((size_t)b * NA + a) * 3 + 0];
                float py = pd_circles[((size_t)b * NA + a) * 3 + 1];
                float pr = pd_circles[((size_t)b * NA + a) * 3 + 2];
                float ddx = gx - px, ddy = gy - py;
                float d  = sqrtf(ddx * ddx + ddy * ddy);
                float rs = gr + pr;
                float iou = fmaxf((rs - d) / rs, 0.f);
                float i2 = iou * iou;
                float s  = pd_scores[((size_t)b * NA + a) * NC + gt_labels[row]];
                am  = s * (i2 * i2 * i2);
                ovv = iou;
            }
        }
        atomicMax(pos_align + row, __float_as_uint(am));
        atomicMax(pos_over  + row, __float_as_uint(ovv));
    }
    am_ws[i] = am;
}

// ============================================================
// K4: write all 5 outputs; score rows via LDS-staged coalesced float4s
// ============================================================
__global__ __launch_bounds__(256) void k_write_scores(
    const int*      __restrict__ gt_labels,
    const float*    __restrict__ gt_bboxes,
    const int*      __restrict__ tgt_ws,
    const float*    __restrict__ am_ws,
    const unsigned* __restrict__ pos_align,
    const unsigned* __restrict__ pos_over,
    float*          __restrict__ out)
{
    __shared__ float s_n[256];
    __shared__ int   s_l[256];

    const int tid = threadIdx.x;
    const int i = blockIdx.x * 256 + tid;     // < BS*NA
    const int b = i / NA;
    int tgt = tgt_ws[i];
    bool fg = (tgt >= 0);
    int jj  = fg ? tgt : 0;
    int row = b * NMAX + jj;

    int lbl = max(gt_labels[row], 0);
    out[O_LAB + i] = (float)lbl;
    out[O_BOX + (size_t)i * 3 + 0] = gt_bboxes[row * 3 + 0];
    out[O_BOX + (size_t)i * 3 + 1] = gt_bboxes[row * 3 + 1];
    out[O_BOX + (size_t)i * 3 + 2] = gt_bboxes[row * 3 + 2];
    out[O_FG + i] = fg ? 1.f : 0.f;
    out[O_GT + i] = (float)jj;

    float nv = 0.f;
    if (fg) {
        float pa = __uint_as_float(pos_align[row]);
        float po = __uint_as_float(pos_over[row]);
        nv = am_ws[i] * po / (pa + EPSF);
    }
    s_n[tid] = nv;
    s_l[tid] = lbl;          // fg=0 -> nv=0 -> row all-zero regardless of lbl
    __syncthreads();

    // coalesced streaming of this block's 256 score rows (256*80 floats)
    float4* __restrict__ scr = (float4*)(out + O_SCR) + (size_t)blockIdx.x * 256 * NQ;
    for (int e = tid; e < 256 * NQ; e += 256) {
        int il = e / NQ;
        int q  = e - il * NQ;
        float nvv = s_n[il];
        int   lb  = s_l[il];
        int   c0  = q * 4;
        float4 vq; vq.x = 0.f; vq.y = 0.f; vq.z = 0.f; vq.w = 0.f;
        if      (lb == c0)     vq.x = nvv;
        else if (lb == c0 + 1) vq.y = nvv;
        else if (lb == c0 + 2) vq.z = nvv;
        else if (lb == c0 + 3) vq.w = nvv;
        scr[e] = vq;
    }
}

// ============================================================
extern "C" void kernel_launch(void* const* d_in, const int* in_sizes, int n_in,
                              void* d_out, int out_size, void* d_ws, size_t ws_size,
                              hipStream_t stream) {
    const float* pd_scores  = (const float*)d_in[0];
    const float* pd_circles = (const float*)d_in[1];
    const float* anc        = (const float*)d_in[2];
    const int*   gt_labels  = (const int*)d_in[3];
    const float* gt_bboxes  = (const float*)d_in[4];
    const float* mask_gt    = (const float*)d_in[5];
    float* out = (float*)d_out;

    char* ws = (char*)d_ws;
    float*    s1val     = (float*)(ws + 0);
    int*      s1idx     = (int*)(ws + 851968);
    unsigned* pack      = (unsigned*)(ws + 1703936);
    int*      tgt_ws    = (int*)(ws + 3854336);
    float*    am_ws     = (float*)(ws + 6004736);
    unsigned* pos_align = (unsigned*)(ws + 8155136);
    unsigned* pos_over  = (unsigned*)(ws + 8159232);

    k_topk_seg<<<BS * NMAX * SEG, 64, 0, stream>>>(pd_scores, pd_circles, anc, gt_labels,
                                                   gt_bboxes, mask_gt, s1val, s1idx,
                                                   pack, pos_align, pos_over);
    k_merge_claim<<<BS * NMAX, 64, 0, stream>>>(s1val, s1idx, anc, gt_bboxes, pack);
    k_resolve<<<(BS * NA) / 256, 256, 0, stream>>>(pd_scores, pd_circles, anc, gt_labels,
                                                   gt_bboxes, mask_gt, pack,
                                                   tgt_ws, am_ws, pos_align, pos_over);
    k_write_scores<<<(BS * NA) / 256, 256, 0, stream>>>(gt_labels, gt_bboxes, tgt_ws, am_ws,
                                                        pos_align, pos_over, out);
}